// Round 11
// baseline (320.273 us; speedup 1.0000x reference)
//
#include <hip/hip_runtime.h>
#include <hip/hip_bf16.h>

#define NND 6890
#define NED 41340

typedef __bf16 bf16x8 __attribute__((ext_vector_type(8)));
typedef float f32x4 __attribute__((ext_vector_type(4)));
typedef unsigned short u16x4 __attribute__((ext_vector_type(4)));

__device__ inline unsigned short f32_bf16(float f) {
  unsigned int u = __float_as_uint(f);
  unsigned int r = (u + 0x7FFFu + ((u >> 16) & 1u)) >> 16;
  return (unsigned short)r;
}
__device__ inline void split2(float v, unsigned short& hi, unsigned short& lo) {
  unsigned short h = f32_bf16(v);
  float hf = __uint_as_float((unsigned int)h << 16);
  hi = h;
  lo = f32_bf16(v - hf);
}
__device__ inline float elu_f(float v) { return v > 0.f ? v : (expf(v) - 1.f); }

// h[c][i] of the previous layer, recomputed from split-K partials (bit-identical
// to the old combine_elu: sum z ascending, then +bias, then elu).
__device__ __forceinline__ float prev_h(const float* __restrict__ P,
                                        const float* __restrict__ bias,
                                        int Fin, int KS, int c, int i) {
  float s = 0.f;
  for (int z = 0; z < KS; ++z) s += P[((size_t)z * NND + c) * Fin + i];
  return elu_f(s + bias[i]);
}

__device__ __forceinline__ void gload_lds16(const void* g, void* l) {
  __builtin_amdgcn_global_load_lds((const __attribute__((address_space(1))) void*)g,
                                   (__attribute__((address_space(3))) void*)l, 16, 0, 0);
}

__global__ void scan_kernel(const int* __restrict__ deg, int* __restrict__ rowptr,
                            int* __restrict__ cursor, float* __restrict__ deginv, int n) {
  __shared__ int part[1024];
  int t = threadIdx.x;
  int CH = (n + 1023) >> 10;
  int base = t * CH;
  int s = 0;
  for (int j = 0; j < CH; ++j) { int i = base + j; if (i < n) s += deg[i]; }
  part[t] = s;
  __syncthreads();
  for (int off = 1; off < 1024; off <<= 1) {
    int v = (t >= off) ? part[t - off] : 0;
    __syncthreads();
    part[t] += v;
    __syncthreads();
  }
  int run = (t == 0) ? 0 : part[t - 1];
  for (int j = 0; j < CH; ++j) {
    int i = base + j;
    if (i < n) {
      rowptr[i] = run; cursor[i] = run;
      int d = deg[i];
      deginv[i] = 1.0f / fmaxf((float)d, 1.0f);
      run += d;
    }
  }
  if (t == 1023) rowptr[n] = part[1023];
}

__global__ void csr_fill_kernel(const int* __restrict__ erow, int* __restrict__ cursor,
                                int* __restrict__ csr, int E) {
  int e = blockIdx.x * blockDim.x + threadIdx.x;
  if (e >= E) return;
  int slot = atomicAdd(&cursor[erow[e]], 1);
  csr[slot] = e;
}

// One prep kernel: [0,323) weight splits; [323,3984) x split; [3984,5712) W2^T cast;
// [5712,5874) edge prep (weights/keys/deg).
__global__ void prep_all_kernel(const float* __restrict__ W_lin, const float* __restrict__ w1,
                                const float* __restrict__ r1, const float* __restrict__ w2,
                                const float* __restrict__ r2, const float* __restrict__ w3,
                                const float* __restrict__ r3, const float* __restrict__ W1,
                                const float* __restrict__ x, const float* __restrict__ W2,
                                const int* __restrict__ erow, const float* __restrict__ pseudo,
                                unsigned short* __restrict__ Th, unsigned short* __restrict__ Tl,
                                unsigned short* __restrict__ xh, unsigned short* __restrict__ xl,
                                unsigned short* __restrict__ W2t,
                                float* __restrict__ ew, int* __restrict__ ek,
                                int* __restrict__ deg) {
  int b = blockIdx.x;
  int tid = threadIdx.x;
  if (b < 323) {
    const int tstart[9] = {0, 17, 30, 31, 81, 83, 283, 291, 323};
    const int jK[8]    = {544, 400, 16, 800, 32, 1600, 64, 128};
    const int jF[8]    = {16, 32, 32, 64, 64, 128, 128, 256};
    const int jldt[8]  = {544, 416, 416, 832, 832, 1664, 1664, 128};
    const int jkoff[8] = {0, 0, 400, 0, 800, 0, 1600, 0};
    const int jdst[8]  = {0, 8704, 8704, 22016, 22016, 75264, 75264, 288256};
    int job = 0;
    while (job < 7 && b >= tstart[job + 1]) ++job;
    int t = b - tstart[job];
    int fxc = (jF[job] + 31) >> 5;
    int kt = t / fxc, ft = t % fxc;
    const float* src;
    switch (job) {
      case 0: src = W_lin; break;
      case 1: src = w1; break;
      case 2: src = r1; break;
      case 3: src = w2; break;
      case 4: src = r2; break;
      case 5: src = w3; break;
      case 6: src = r3; break;
      default: src = W1; break;
    }
    int K = jK[job], F = jF[job], ldt = jldt[job], koff = jkoff[job];
    unsigned short* th = Th + jdst[job];
    unsigned short* tl = Tl + jdst[job];
    int k0 = kt * 32, c0 = ft * 32;
    __shared__ float tbuf[32][33];
    int tx = tid & 31, ty = tid >> 5;
    for (int j = ty; j < 32; j += 8) {
      int gk = k0 + j, gc = c0 + tx;
      tbuf[j][tx] = (gk < K && gc < F) ? src[(size_t)gk * F + gc] : 0.f;
    }
    __syncthreads();
    for (int j = ty; j < 32; j += 8) {
      int gc = c0 + j, gk = k0 + tx;
      if (gc < F && gk < K) {
        unsigned short h, lo2;
        split2(tbuf[tx][j], h, lo2);
        th[(size_t)gc * ldt + koff + gk] = h;
        tl[(size_t)gc * ldt + koff + gk] = lo2;
      }
    }
  } else if (b < 3984) {
    int i = (b - 323) * 256 + tid;   // f32x4 units, n4 = NND*136
    if (i < NND * 136) {
      f32x4 v = *(const f32x4*)(x + 4 * (size_t)i);
      u16x4 h, l;
#pragma unroll
      for (int j = 0; j < 4; ++j) {
        unsigned short hh, ll;
        split2(v[j], hh, ll);
        h[j] = hh; l[j] = ll;
      }
      *(u16x4*)(xh + 4 * (size_t)i) = h;
      *(u16x4*)(xl + 4 * (size_t)i) = l;
    }
  } else if (b < 5712) {
    int t = b - 3984;
    int c0 = (t % 216) * 32, k0 = (t / 216) * 32;
    __shared__ float tb2[32][33];
    int tx = tid & 31, ty = tid >> 5;
    for (int j = ty; j < 32; j += 8) {
      int gk = k0 + j, gc = c0 + tx;
      tb2[j][tx] = (gk < 256 && gc < NND) ? W2[(size_t)gk * NND + gc] : 0.f;
    }
    __syncthreads();
    for (int j = ty; j < 32; j += 8) {
      int gc = c0 + j, gk = k0 + tx;
      if (gc < NND && gk < 256) W2t[(size_t)gc * 256 + gk] = f32_bf16(tb2[tx][j]);
    }
  } else {
    int e = (b - 5712) * 256 + tid;
    if (e < NED) {
      float p0 = pseudo[2 * e + 0] * 4.0f;
      float p1 = pseudo[2 * e + 1] * 4.0f;
      int i0 = (int)floorf(p0); i0 = i0 < 0 ? 0 : (i0 > 3 ? 3 : i0);
      int i1 = (int)floorf(p1); i1 = i1 < 0 ? 0 : (i1 > 3 ? 3 : i1);
      float f0 = p0 - (float)i0, f1 = p1 - (float)i1;
      ew[4 * e + 0] = (1.f - f0) * (1.f - f1);
      ew[4 * e + 1] = f0 * (1.f - f1);
      ew[4 * e + 2] = (1.f - f0) * f1;
      ew[4 * e + 3] = f0 * f1;
      int bb = i0 + 5 * i1;
      ek[4 * e + 0] = bb; ek[4 * e + 1] = bb + 1; ek[4 * e + 2] = bb + 5; ek[4 * e + 3] = bb + 6;
      atomicAdd(&deg[erow[e]], 1);
    }
  }
}

// B-row build, atomic-free; previous-layer h recomputed from split-K partials P
// (combine_elu folded in). Outputs bf16 hi/lo planes [N][26*Fin].
__global__ void b_build_kernel(const float* __restrict__ P, const float* __restrict__ bias,
                               const int* __restrict__ ecol,
                               const float* __restrict__ ew4, const int* __restrict__ ek4,
                               const int* __restrict__ rowptr, const int* __restrict__ csr,
                               const float* __restrict__ deginv,
                               unsigned short* __restrict__ Bh, unsigned short* __restrict__ Bl,
                               int Fin, int KS) {
  extern __shared__ float lds[];  // 4 planes x 25*Fin floats
  int r = blockIdx.x;
  int T = blockDim.x;  // 4*Fin
  int tid = threadIdx.x;
  int nb = 25 * Fin;
  int j = tid / Fin;
  int i = tid - j * Fin;
  float* plane = lds + j * nb;
  for (int t = tid; t < 4 * nb; t += T) lds[t] = 0.f;
  __syncthreads();
  int p0 = rowptr[r], p1 = rowptr[r + 1];
  for (int p = p0 + j; p < p1; p += 4) {
    int e = csr[p];
    int c = ecol[e];
    float xv = prev_h(P, bias, Fin, KS, c, i);
    f32x4 wv = *(const f32x4*)(ew4 + 4 * e);
    int4 kv = *(const int4*)(ek4 + 4 * e);
    plane[kv.x * Fin + i] += wv[0] * xv;
    plane[kv.y * Fin + i] += wv[1] * xv;
    plane[kv.z * Fin + i] += wv[2] * xv;
    plane[kv.w * Fin + i] += wv[3] * xv;
  }
  __syncthreads();
  float dinv = deginv[r];
  int tot = nb + Fin;  // = 26*Fin = Kd
  for (int t = tid; t < tot; t += T) {
    float v;
    if (t < nb)
      v = (lds[t] + lds[nb + t] + lds[2 * nb + t] + lds[3 * nb + t]) * dinv;
    else
      v = prev_h(P, bias, Fin, KS, r, t - nb);
    unsigned short h, l;
    split2(v, h, l);
    Bh[(size_t)r * tot + t] = h;
    Bl[(size_t)r * tot + t] = l;
  }
}

// Partial GEMM (bf16x3) over K-slice z: P[z][M][F] = A @ W.
template <int BN>
__global__ __launch_bounds__(256) void gemm_x3_partial_kernel(
    const unsigned short* __restrict__ Ah, const unsigned short* __restrict__ Al,
    const unsigned short* __restrict__ Wh, const unsigned short* __restrict__ Wl,
    float* __restrict__ P, int M, int Kd, int F, int KS) {
  constexpr int AE = 64 * 32;
  constexpr int WE = BN * 32;
  __shared__ __align__(16) unsigned short lds[2][2 * AE + 2 * WE];
  int tid = threadIdx.x;
  int wave = tid >> 6, lane = tid & 63;
  int g = lane >> 4, r = lane & 15;
  int row0 = blockIdx.y * 64;
  int col0 = blockIdx.x * BN;
  int z = blockIdx.z;
  int nt = Kd >> 5;
  int ta = z * nt / KS, tb = (z + 1) * nt / KS;

  auto STAGE = [&](int buf, int kb) {
    {
      int rr = tid >> 2, pos = tid & 3;
      int c = (pos - rr) & 3;
      int gra = row0 + rr; if (gra >= M) gra = M - 1;
      size_t so = (size_t)gra * Kd + kb + c * 8;
      gload_lds16(Ah + so, &lds[buf][wave * 512]);
      gload_lds16(Al + so, &lds[buf][AE + wave * 512]);
    }
#pragma unroll
    for (int it = 0; it < (4 * BN + 255) / 256; ++it) {
      int idx = it * 256 + tid;
      if (idx < 4 * BN) {
        int rr = idx >> 2, pos = idx & 3;
        int c = (pos - rr) & 3;
        size_t so = (size_t)(col0 + rr) * Kd + kb + c * 8;
        gload_lds16(Wh + so, &lds[buf][2 * AE + (it * 256 + wave * 64) * 8]);
        gload_lds16(Wl + so, &lds[buf][2 * AE + WE + (it * 256 + wave * 64) * 8]);
      }
    }
  };

  constexpr int NF = BN / 16;
  f32x4 acc[NF];
#pragma unroll
  for (int n = 0; n < NF; ++n)
#pragma unroll
    for (int q = 0; q < 4; ++q) acc[n][q] = 0.f;

  int n = tb - ta;
  int rA = wave * 16 + r;
  int aoff = rA * 32 + ((g + rA) & 3) * 8;

  STAGE(0, ta * 32);
  __syncthreads();
  for (int tt = 0; tt < n; ++tt) {
    int buf = tt & 1;
    if (tt + 1 < n) STAGE(buf ^ 1, (ta + tt + 1) * 32);
    bf16x8 fah = *(const bf16x8*)&lds[buf][aoff];
    bf16x8 fal = *(const bf16x8*)&lds[buf][AE + aoff];
#pragma unroll
    for (int nn = 0; nn < NF; ++nn) {
      int rW = nn * 16 + r;
      int woff = rW * 32 + ((g + rW) & 3) * 8;
      bf16x8 fbh = *(const bf16x8*)&lds[buf][2 * AE + woff];
      bf16x8 fbl = *(const bf16x8*)&lds[buf][2 * AE + WE + woff];
      acc[nn] = __builtin_amdgcn_mfma_f32_16x16x32_bf16(fah, fbh, acc[nn], 0, 0, 0);
      acc[nn] = __builtin_amdgcn_mfma_f32_16x16x32_bf16(fal, fbh, acc[nn], 0, 0, 0);
      acc[nn] = __builtin_amdgcn_mfma_f32_16x16x32_bf16(fah, fbl, acc[nn], 0, 0, 0);
    }
    __syncthreads();
  }
#pragma unroll
  for (int nn = 0; nn < NF; ++nn) {
    int gc = col0 + nn * 16 + r;
#pragma unroll
    for (int q = 0; q < 4; ++q) {
      int gr = row0 + wave * 16 + g * 4 + q;
      if (gr < M) P[((size_t)z * M + gr) * F + gc] = acc[nn][q];
    }
  }
}

// out = elu(sum_z P[z] + bias); bf16 or hi/lo-plane output (kept for h3/h4 only)
__global__ __launch_bounds__(256) void combine_elu_kernel(
    const float* __restrict__ P, const float* __restrict__ bias,
    unsigned short* __restrict__ outB,
    unsigned short* __restrict__ outH, unsigned short* __restrict__ outL,
    int M, int F, int KS) {
  int i4 = blockIdx.x * 256 + threadIdx.x;
  int fv = F >> 2;
  int total = M * fv;
  if (i4 >= total) return;
  int gr = i4 / fv, c4 = (i4 - gr * fv) * 4;
  f32x4 s = {0.f, 0.f, 0.f, 0.f};
  for (int z = 0; z < KS; ++z)
    s += *(const f32x4*)(P + ((size_t)z * M + gr) * F + c4);
  f32x4 bv = *(const f32x4*)(bias + c4);
#pragma unroll
  for (int j = 0; j < 4; ++j) s[j] = elu_f(s[j] + bv[j]);
  if (outH) {
    u16x4 h, l;
#pragma unroll
    for (int j = 0; j < 4; ++j) {
      unsigned short hh, ll;
      split2(s[j], hh, ll);
      h[j] = hh; l[j] = ll;
    }
    *(u16x4*)(outH + (size_t)gr * F + c4) = h;
    *(u16x4*)(outL + (size_t)gr * F + c4) = l;
  } else {
    u16x4 o;
#pragma unroll
    for (int j = 0; j < 4; ++j) o[j] = f32_bf16(s[j]);
    *(u16x4*)(outB + (size_t)gr * F + c4) = o;
  }
}

// Final layer GEMM: 128x128 tile, BK=32 dbuf (32 KB LDS), bank-even rotation,
// bijective XCD-chunked block swizzle (m204), 1D grid of 54*54.
// MODE 0: online-softmax partials (m,s); MODE 1: two-round LDS stash + coalesced
// f32x4 stores of logit + bias - lse.
template <int MODE>
__global__ __launch_bounds__(256) void gemm_final_kernel(
    const unsigned short* __restrict__ A, const unsigned short* __restrict__ Bt,
    const float* __restrict__ bias, const float* __restrict__ lse,
    float* __restrict__ outp, int M, int N) {
  __shared__ __align__(16) unsigned short lds[2][2][4096];  // 32 KB
  int tid = threadIdx.x;
  int w = tid >> 6, l = tid & 63;
  // XCD swizzle: consecutive wg within a chunk share an XCD -> A-panel L2 reuse
  int orig = blockIdx.x;
  const int nwg = 54 * 54, q = nwg >> 3, r8 = nwg & 7;
  int xcd = orig & 7, k = orig >> 3;
  int base = (xcd < r8) ? xcd * (q + 1) : r8 * (q + 1) + (xcd - r8) * q;
  int wg = base + k;
  int by = wg / 54, bx = wg - by * 54;
  int row0 = by * 128, col0 = bx * 128;

  auto STAGE = [&](int buf, int kb) {
#pragma unroll
    for (int it = 0; it < 2; ++it) {
      int idx = it * 256 + tid;            // chunk id 0..511 (128 rows x 4)
      int rr = idx >> 2, pos = idx & 3;
      int c = (pos - rr) & 3;
      int gra = row0 + rr; if (gra >= M) gra = M - 1;
      int grb = col0 + rr; if (grb >= N) grb = N - 1;
      gload_lds16(A + (size_t)gra * 256 + kb + c * 8, &lds[buf][0][(it * 256 + w * 64) * 8]);
      gload_lds16(Bt + (size_t)grb * 256 + kb + c * 8, &lds[buf][1][(it * 256 + w * 64) * 8]);
    }
  };

  int wm = w >> 1, wn = w & 1;
  int g = l >> 4, r = l & 15;

  f32x4 acc[4][4];
#pragma unroll
  for (int mi = 0; mi < 4; ++mi)
#pragma unroll
    for (int ni = 0; ni < 4; ++ni)
#pragma unroll
      for (int q2 = 0; q2 < 4; ++q2) acc[mi][ni][q2] = 0.f;

  STAGE(0, 0);
  __syncthreads();
#pragma unroll
  for (int ks = 0; ks < 8; ++ks) {
    int buf = ks & 1;
    if (ks < 7) STAGE(buf ^ 1, (ks + 1) * 32);
    bf16x8 fa[4], fb[4];
#pragma unroll
    for (int mi = 0; mi < 4; ++mi) {
      int rA = wm * 64 + mi * 16 + r;
      fa[mi] = *(const bf16x8*)&lds[buf][0][rA * 32 + ((g + rA) & 3) * 8];
    }
#pragma unroll
    for (int ni = 0; ni < 4; ++ni) {
      int rB = wn * 64 + ni * 16 + r;
      fb[ni] = *(const bf16x8*)&lds[buf][1][rB * 32 + ((g + rB) & 3) * 8];
    }
#pragma unroll
    for (int mi = 0; mi < 4; ++mi)
#pragma unroll
      for (int ni = 0; ni < 4; ++ni)
        acc[mi][ni] = __builtin_amdgcn_mfma_f32_16x16x32_bf16(fb[ni], fa[mi], acc[mi][ni], 0, 0, 0);
    __syncthreads();
  }

  if (MODE == 0) {
    float bb[4][4];
#pragma unroll
    for (int ni = 0; ni < 4; ++ni) {
      int gc0 = col0 + wn * 64 + ni * 16 + g * 4;
#pragma unroll
      for (int q2 = 0; q2 < 4; ++q2)
        bb[ni][q2] = (gc0 + q2 < N) ? bias[gc0 + q2] : 0.f;
    }
#pragma unroll
    for (int mi = 0; mi < 4; ++mi) {
      int gr = row0 + wm * 64 + mi * 16 + r;
      float vv[4][4];
      float mloc = -3e38f;
#pragma unroll
      for (int ni = 0; ni < 4; ++ni) {
        int gc0 = col0 + wn * 64 + ni * 16 + g * 4;
#pragma unroll
        for (int q2 = 0; q2 < 4; ++q2) {
          float v = (gc0 + q2 < N) ? (acc[mi][ni][q2] + bb[ni][q2]) : -3e38f;
          vv[ni][q2] = v;
          mloc = fmaxf(mloc, v);
        }
      }
      float sloc = 0.f;
#pragma unroll
      for (int ni = 0; ni < 4; ++ni) {
        int gc0 = col0 + wn * 64 + ni * 16 + g * 4;
#pragma unroll
        for (int q2 = 0; q2 < 4; ++q2)
          if (gc0 + q2 < N) sloc += __expf(vv[ni][q2] - mloc);
      }
#pragma unroll
      for (int off = 16; off < 64; off <<= 1) {
        float mo = __shfl_xor(mloc, off);
        float so = __shfl_xor(sloc, off);
        float mn = fmaxf(mloc, mo);
        sloc = sloc * __expf(mloc - mn) + so * __expf(mo - mn);
        mloc = mn;
      }
      if (g == 0 && gr < M) {
        int hb = bx * 2 + wn;
        *(float2*)(outp + 2 * ((size_t)hb * M + gr)) = make_float2(mloc, sloc);
      }
    }
  } else {
    float* LBUF = (float*)&lds[0][0][0];  // 8192 floats
#pragma unroll
    for (int p = 0; p < 2; ++p) {
      __syncthreads();
#pragma unroll
      for (int mh = 0; mh < 2; ++mh) {
        int mi = 2 * p + mh;
        int lr = wm * 32 + mh * 16 + r;
#pragma unroll
        for (int ni = 0; ni < 4; ++ni) {
          int ch = wn * 16 + ni * 4 + g;
          int u = (ch + lr) & 31;
          *(f32x4*)(LBUF + lr * 128 + u * 4) = acc[mi][ni];
        }
      }
      __syncthreads();
#pragma unroll
      for (int t = 0; t < 8; ++t) {
        int unit = t * 256 + tid;
        int lr = unit >> 5, ch = unit & 31;
        int gr = row0 + (lr >> 5) * 64 + p * 32 + ((lr >> 4) & 1) * 16 + (lr & 15);
        if (gr >= M) continue;
        int u = (ch + lr) & 31;
        f32x4 v = *(const f32x4*)(LBUF + lr * 128 + u * 4);
        float L = lse[gr];
        int gc0 = col0 + ch * 4;
        if (gc0 + 4 <= N) {
          f32x4 bv = *(const f32x4*)(bias + gc0);
#pragma unroll
          for (int q2 = 0; q2 < 4; ++q2) v[q2] = v[q2] + bv[q2] - L;
          *(f32x4*)(outp + (size_t)gr * N + gc0) = v;
        } else {
#pragma unroll
          for (int q2 = 0; q2 < 4; ++q2)
            if (gc0 + q2 < N) outp[(size_t)gr * N + gc0 + q2] = v[q2] + bias[gc0 + q2] - L;
        }
      }
    }
  }
}

// lse[row] = online-merge of NH (m,s) partials
__global__ __launch_bounds__(256) void lse_kernel(const float* __restrict__ stats,
                                                  float* __restrict__ lse, int M, int NH) {
  int row = blockIdx.x * 256 + threadIdx.x;
  if (row >= M) return;
  float m = -3e38f, s = 0.f;
  for (int hb = 0; hb < NH; ++hb) {
    float2 v = *(const float2*)(stats + 2 * ((size_t)hb * M + row));
    float mn = fmaxf(m, v.x);
    s = s * __expf(m - mn) + v.y * __expf(v.x - mn);
    m = mn;
  }
  lse[row] = m + logf(s);
}

extern "C" void kernel_launch(void* const* d_in, const int* in_sizes, int n_in,
                              void* d_out, int out_size, void* d_ws, size_t ws_size,
                              hipStream_t stream) {
  const int N = NND, E = NED;
  const float* x      = (const float*)d_in[0];
  const int*   ei     = (const int*)d_in[1];
  const float* pseudo = (const float*)d_in[2];
  const float* W_lin  = (const float*)d_in[3];
  const float* b_lin  = (const float*)d_in[4];
  const float* w1  = (const float*)d_in[5];
  const float* r1  = (const float*)d_in[6];
  const float* bi1 = (const float*)d_in[7];
  const float* w2  = (const float*)d_in[8];
  const float* r2  = (const float*)d_in[9];
  const float* bi2 = (const float*)d_in[10];
  const float* w3  = (const float*)d_in[11];
  const float* r3  = (const float*)d_in[12];
  const float* bi3 = (const float*)d_in[13];
  const float* W1  = (const float*)d_in[14];
  const float* b1  = (const float*)d_in[15];
  const float* W2  = (const float*)d_in[16];
  const float* b2  = (const float*)d_in[17];
  const int* erow = ei;
  const int* ecol = ei + E;

  // Scratch carved out of d_out (dead before pass C overwrites all of d_out)
  char* scratch = (char*)d_out;
  size_t off = 0;
  auto alloc = [&](size_t bytes) -> void* {
    void* p = scratch + off;
    off = (off + bytes + 255) & ~(size_t)255;
    return p;
  };
  unsigned short* Bh = (unsigned short*)alloc((size_t)N * 1664 * 2);
  unsigned short* Bl = (unsigned short*)alloc((size_t)N * 1664 * 2);
  unsigned short* h3h = (unsigned short*)alloc((size_t)N * 128 * 2);
  unsigned short* h3l = (unsigned short*)alloc((size_t)N * 128 * 2);
  unsigned short* xh  = (unsigned short*)alloc((size_t)N * 544 * 2);
  unsigned short* xl  = (unsigned short*)alloc((size_t)N * 544 * 2);
  unsigned short* Wth = (unsigned short*)alloc((size_t)321024 * 2);
  unsigned short* Wtl = (unsigned short*)alloc((size_t)321024 * 2);
  float* P0 = (float*)alloc((size_t)4 * N * 16 * 4);
  float* P1 = (float*)alloc((size_t)4 * N * 32 * 4);
  float* P2 = (float*)alloc((size_t)4 * N * 64 * 4);
  float* P3 = (float*)alloc((size_t)4 * N * 128 * 4);
  float* P4 = (float*)alloc((size_t)2 * N * 256 * 4);
  float* stats  = (float*)alloc((size_t)108 * N * 2 * 4);
  float* ew     = (float*)alloc((size_t)E * 4 * 4);
  int*   ek     = (int*)alloc((size_t)E * 4 * 4);
  int*   deg    = (int*)alloc((size_t)N * 4);
  float* deginv = (float*)alloc((size_t)N * 4);
  int*   rowptr = (int*)alloc((size_t)(N + 1) * 4);
  int*   cursor = (int*)alloc((size_t)N * 4);
  int*   csr    = (int*)alloc((size_t)E * 4);

  // Buffers alive during pass C go in d_ws
  unsigned short* h4b = (unsigned short*)d_ws;                                 // N*256 bf16
  unsigned short* W2t = (unsigned short*)((char*)d_ws + (size_t)N * 256 * 2);  // N*256 bf16
  float* lse = (float*)((char*)d_ws + (size_t)N * 256 * 4);                    // N f32

  // ---- prep: memset deg, then one wide kernel (splits + W2^T + edge prep) ----
  hipMemsetAsync(deg, 0, (size_t)N * 4, stream);
  prep_all_kernel<<<5874, 256, 0, stream>>>(W_lin, w1, r1, w2, r2, w3, r3, W1, x, W2,
                                            erow, pseudo, Wth, Wtl, xh, xl, W2t, ew, ek, deg);
  scan_kernel<<<1, 1024, 0, stream>>>(deg, rowptr, cursor, deginv, N);
  csr_fill_kernel<<<(E + 255) / 256, 256, 0, stream>>>(erow, cursor, csr, E);

  // ---- stage 0: P0 = x @ W_lin (split-K partials; elu folded into b_build1) ----
  gemm_x3_partial_kernel<16><<<dim3(1, 108, 4), 256, 0, stream>>>(xh, xl, Wth + 0, Wtl + 0, P0, N, 544, 16, 4);

  // ---- spline layer 1 (16 -> 32), Kd = 416 ----
  b_build_kernel<<<N, 64, 4 * 25 * 16 * 4, stream>>>(P0, b_lin, ecol, ew, ek, rowptr, csr, deginv, Bh, Bl, 16, 4);
  gemm_x3_partial_kernel<32><<<dim3(1, 108, 4), 256, 0, stream>>>(Bh, Bl, Wth + 8704, Wtl + 8704, P1, N, 416, 32, 4);

  // ---- spline layer 2 (32 -> 64), Kd = 832 ----
  b_build_kernel<<<N, 128, 4 * 25 * 32 * 4, stream>>>(P1, bi1, ecol, ew, ek, rowptr, csr, deginv, Bh, Bl, 32, 4);
  gemm_x3_partial_kernel<64><<<dim3(1, 108, 4), 256, 0, stream>>>(Bh, Bl, Wth + 22016, Wtl + 22016, P2, N, 832, 64, 4);

  // ---- spline layer 3 (64 -> 128), Kd = 1664 ----
  b_build_kernel<<<N, 256, 4 * 25 * 64 * 4, stream>>>(P2, bi2, ecol, ew, ek, rowptr, csr, deginv, Bh, Bl, 64, 4);
  gemm_x3_partial_kernel<128><<<dim3(1, 108, 4), 256, 0, stream>>>(Bh, Bl, Wth + 75264, Wtl + 75264, P3, N, 1664, 128, 4);
  combine_elu_kernel<<<(N * 32 + 255) / 256, 256, 0, stream>>>(P3, bi3, nullptr, h3h, h3l, N, 128, 4);

  // ---- stage 4: h4 = elu(h3 @ W1 + b1) -> bf16 ----
  gemm_x3_partial_kernel<128><<<dim3(2, 108, 2), 256, 0, stream>>>(h3h, h3l, Wth + 288256, Wtl + 288256, P4, N, 128, 256, 2);
  combine_elu_kernel<<<(N * 64 + 255) / 256, 256, 0, stream>>>(P4, b1, h4b, nullptr, nullptr, N, 256, 2);

  // ---- pass A: softmax partials ----
  gemm_final_kernel<0><<<dim3(54 * 54), 256, 0, stream>>>(h4b, W2t, b2, nullptr, stats, N, N);

  // ---- pass B: lse per row ----
  lse_kernel<<<(N + 255) / 256, 256, 0, stream>>>(stats, lse, N, 108);

  // ---- pass C: recompute logits, write logit - lse ----
  gemm_final_kernel<1><<<dim3(54 * 54), 256, 0, stream>>>(h4b, W2t, b2, lse, (float*)d_out, N, N);

  (void)in_sizes; (void)n_in; (void)out_size; (void)ws_size;
}